// Round 2
// baseline (844.856 us; speedup 1.0000x reference)
//
#include <hip/hip_runtime.h>

#define NN 50000
#define DD 128
#define EE 100000
#define ET (EE + NN)

typedef __attribute__((ext_vector_type(4))) float f32x4;
typedef __attribute__((ext_vector_type(2))) float f32x2;
typedef __attribute__((ext_vector_type(8))) short bf16x8;
typedef __attribute__((ext_vector_type(4))) unsigned short u16x4;

static __device__ __forceinline__ unsigned short f2bf(float f) {
  union { float f; unsigned int u; } v; v.f = f;
  unsigned int r = (v.u + 0x7FFFu + ((v.u >> 16) & 1u)) >> 16;
  return (unsigned short)r;
}
static __device__ __forceinline__ float bf2f(unsigned short s) {
  union { unsigned int u; float f; } v; v.u = ((unsigned int)s) << 16;
  return v.f;
}

// ---------------- CSR build (edge_index is int32: [2,E] = src row then dst row) ----------------
__global__ void k_count(const int* __restrict__ ei, int* __restrict__ counts) {
  int i = blockIdx.x * blockDim.x + threadIdx.x;
  if (i >= ET) return;
  int dst = (i < EE) ? ei[EE + i] : (i - EE);
  if (dst < 0 || dst >= NN) return;  // defensive
  atomicAdd(&counts[dst], 1);
}

__global__ __launch_bounds__(1024) void k_scan(const int* __restrict__ counts,
                                               int* __restrict__ offs,
                                               int* __restrict__ cursor) {
  __shared__ int buf[1024];
  const int tid = threadIdx.x;
  int carry = 0;
  for (int base = 0; base < NN; base += 1024) {
    int i = base + tid;
    int v = (i < NN) ? counts[i] : 0;
    buf[tid] = v;
    __syncthreads();
    for (int off = 1; off < 1024; off <<= 1) {
      int t = (tid >= off) ? buf[tid - off] : 0;
      __syncthreads();
      buf[tid] += t;
      __syncthreads();
    }
    int incl = buf[tid];
    int total = buf[1023];
    if (i < NN) { int e = carry + incl - v; offs[i] = e; cursor[i] = e; }
    carry += total;
    __syncthreads();
  }
  if (tid == 0) offs[NN] = carry;
}

__global__ void k_fill(const int* __restrict__ ei, int* __restrict__ cursor,
                       int* __restrict__ srcs) {
  int i = blockIdx.x * blockDim.x + threadIdx.x;
  if (i >= ET) return;
  int src, dst;
  if (i < EE) { src = ei[i]; dst = ei[EE + i]; }
  else { src = dst = i - EE; }
  if (dst < 0 || dst >= NN) return;        // defensive
  if (src < 0 || src >= NN) src = dst;     // defensive
  int pos = atomicAdd(&cursor[dst], 1);
  if (pos >= 0 && pos < ET) srcs[pos] = src;
}

// ---------------- GEMM: C(bf16)[M,Nout] = A(f32)[M,128] @ B(f32)[128,Nout] ----------------
// grid: (ceil(M/128), Nout/128, 2)  block: 256
__global__ __launch_bounds__(256) void gemm_xlr(
    const float* __restrict__ A, const float* __restrict__ Bl, const float* __restrict__ Br,
    unsigned short* __restrict__ Cl, unsigned short* __restrict__ Cr, int M, int Nout) {
  const float* B = (blockIdx.z == 0) ? Bl : Br;
  unsigned short* C = (blockIdx.z == 0) ? Cl : Cr;
  const int m0 = blockIdx.x * 128;
  const int n0 = blockIdx.y * 128;
  __shared__ unsigned short As[128][136];  // [row][k], +8 pad
  __shared__ unsigned short Bs[128][136];  // [col][k] (transposed), +8 pad
  const int tid = threadIdx.x;

  // stage A (f32 -> bf16), rows m0..m0+127, k 0..127
  for (int it = 0; it < 16; ++it) {
    int idx = tid + it * 256;     // 0..4095
    int r = idx >> 5;             // row in tile
    int k4 = (idx & 31) << 2;     // k start
    int gr = m0 + r;
    f32x4 v = {0.f, 0.f, 0.f, 0.f};
    if (gr < M) v = *(const f32x4*)(A + (size_t)gr * DD + k4);
    u16x4 w;
    w.x = f2bf(v.x); w.y = f2bf(v.y); w.z = f2bf(v.z); w.w = f2bf(v.w);
    *(u16x4*)&As[r][k4] = w;
  }
  // stage B transposed: Bs[c][k] = B[k][n0+c]
  for (int it = 0; it < 16; ++it) {
    int idx = tid + it * 256;
    int k = idx >> 5;
    int c4 = (idx & 31) << 2;
    f32x4 v = *(const f32x4*)(B + (size_t)k * Nout + n0 + c4);
    Bs[c4 + 0][k] = f2bf(v.x);
    Bs[c4 + 1][k] = f2bf(v.y);
    Bs[c4 + 2][k] = f2bf(v.z);
    Bs[c4 + 3][k] = f2bf(v.w);
  }
  __syncthreads();

  const int wave = tid >> 6, lane = tid & 63;
  const int wr = (wave >> 1) * 64, wc = (wave & 1) * 64;
  const int lr = lane & 15, lk = (lane >> 4) << 3;
  f32x4 acc[4][4];
#pragma unroll
  for (int i = 0; i < 4; ++i)
#pragma unroll
    for (int j = 0; j < 4; ++j) acc[i][j] = (f32x4){0.f, 0.f, 0.f, 0.f};

#pragma unroll
  for (int k0 = 0; k0 < 128; k0 += 32) {
    bf16x8 af[4], bfr[4];
#pragma unroll
    for (int mi = 0; mi < 4; ++mi) af[mi] = *(const bf16x8*)&As[wr + mi * 16 + lr][k0 + lk];
#pragma unroll
    for (int ni = 0; ni < 4; ++ni) bfr[ni] = *(const bf16x8*)&Bs[wc + ni * 16 + lr][k0 + lk];
#pragma unroll
    for (int mi = 0; mi < 4; ++mi)
#pragma unroll
      for (int ni = 0; ni < 4; ++ni)
        acc[mi][ni] = __builtin_amdgcn_mfma_f32_16x16x32_bf16(af[mi], bfr[ni], acc[mi][ni], 0, 0, 0);
  }

  // C/D layout: col = lane&15, row = (lane>>4)*4 + reg
#pragma unroll
  for (int mi = 0; mi < 4; ++mi) {
#pragma unroll
    for (int ni = 0; ni < 4; ++ni) {
      int col = n0 + wc + ni * 16 + lr;
#pragma unroll
      for (int j = 0; j < 4; ++j) {
        int row = m0 + wr + mi * 16 + ((lane >> 4) << 2) + j;
        if (row < M) C[(size_t)row * Nout + col] = f2bf(acc[mi][ni][j]);
      }
    }
  }
}

// ---------------- fused score + online softmax + aggregation ----------------
// one WAVE per dst node (block = 4 waves = 4 nodes); wave handles ALL heads;
// lane handles 2 channels. Head-mean is lane-local -> no LDS, no barriers.
template <int H>
__global__ __launch_bounds__(256) void gat_agg(
    const unsigned short* __restrict__ xl, const unsigned short* __restrict__ xr,
    const int* __restrict__ offs, const int* __restrict__ srcs,
    const float* __restrict__ att, const float* __restrict__ bias,
    const float* __restrict__ resid, float* __restrict__ out, int do_elu) {
  const int wave = threadIdx.x >> 6, lane = threadIdx.x & 63;
  const int n = blockIdx.x * 4 + wave;
  if (n >= NN) return;
  const int c0 = lane << 1;

  float xr0[H], xr1[H], a0[H], a1[H];
  float acc0[H], acc1[H], mx[H], dn[H];
#pragma unroll
  for (int h = 0; h < H; ++h) {
    unsigned int u = *(const unsigned int*)(xr + ((size_t)n * H + h) * DD + c0);
    xr0[h] = bf2f((unsigned short)(u & 0xFFFFu));
    xr1[h] = bf2f((unsigned short)(u >> 16));
    a0[h] = att[h * DD + c0];
    a1[h] = att[h * DD + c0 + 1];
    acc0[h] = 0.f; acc1[h] = 0.f; mx[h] = -1e30f; dn[h] = 0.f;
  }

  const int e0 = offs[n], e1 = offs[n + 1];
  for (int j = e0; j < e1; ++j) {
    int s = srcs[j];
#pragma unroll
    for (int h = 0; h < H; ++h) {
      unsigned int u = *(const unsigned int*)(xl + ((size_t)s * H + h) * DD + c0);
      float x0 = bf2f((unsigned short)(u & 0xFFFFu));
      float x1 = bf2f((unsigned short)(u >> 16));
      float z0 = x0 + xr0[h]; z0 = (z0 > 0.f) ? z0 : 0.2f * z0;
      float z1 = x1 + xr1[h]; z1 = (z1 > 0.f) ? z1 : 0.2f * z1;
      float p = z0 * a0[h] + z1 * a1[h];
#pragma unroll
      for (int m = 1; m < 64; m <<= 1) p += __shfl_xor(p, m, 64);
      float mnew = fmaxf(mx[h], p);
      float sc = __expf(mx[h] - mnew);
      float w = __expf(p - mnew);
      acc0[h] = acc0[h] * sc + w * x0;
      acc1[h] = acc1[h] * sc + w * x1;
      dn[h] = dn[h] * sc + w;
      mx[h] = mnew;
    }
  }

  float s0 = 0.f, s1 = 0.f;
#pragma unroll
  for (int h = 0; h < H; ++h) {
    float inv = 1.f / dn[h];
    s0 += acc0[h] * inv;
    s1 += acc1[h] * inv;
  }
  const float invH = 1.f / (float)H;
  float o0 = s0 * invH + bias[c0] + resid[(size_t)n * DD + c0];
  float o1 = s1 * invH + bias[c0 + 1] + resid[(size_t)n * DD + c0 + 1];
  if (do_elu) {
    o0 = (o0 > 0.f) ? o0 : expm1f(o0);
    o1 = (o1 > 0.f) ? o1 : expm1f(o1);
  }
  f32x2 o; o.x = o0; o.y = o1;
  *(f32x2*)(out + (size_t)n * DD + c0) = o;
}

extern "C" void kernel_launch(void* const* d_in, const int* in_sizes, int n_in,
                              void* d_out, int out_size, void* d_ws, size_t ws_size,
                              hipStream_t stream) {
  const float* x = (const float*)d_in[0];
  const int* ei = (const int*)d_in[1];     // int32 on device per harness convention
  const float* W1l = (const float*)d_in[2];
  const float* W1r = (const float*)d_in[3];
  const float* att1 = (const float*)d_in[4];
  const float* b1 = (const float*)d_in[5];
  const float* W2l = (const float*)d_in[6];
  const float* W2r = (const float*)d_in[7];
  const float* att2 = (const float*)d_in[8];
  const float* b2 = (const float*)d_in[9];
  const float* W3l = (const float*)d_in[10];
  const float* W3r = (const float*)d_in[11];
  const float* att3 = (const float*)d_in[12];
  const float* b3 = (const float*)d_in[13];
  float* out = (float*)d_out;

  char* p = (char*)d_ws;
  auto carve = [&](size_t bytes) {
    char* r = p;
    p += (bytes + 255) & ~(size_t)255;
    return r;
  };
  unsigned short* xl = (unsigned short*)carve((size_t)NN * 1024 * 2);
  unsigned short* xr = (unsigned short*)carve((size_t)NN * 1024 * 2);
  int* counts = (int*)carve((size_t)NN * 4);
  int* offs = (int*)carve(((size_t)NN + 1) * 4);
  int* cursor = (int*)carve((size_t)NN * 4);
  int* srcs = (int*)carve((size_t)ET * 4);
  size_t needed = (size_t)(p - (char*)d_ws);
  if (needed > ws_size) return;  // graceful fail (absmax mismatch) instead of OOB fault

  hipMemsetAsync(counts, 0, (size_t)NN * 4, stream);
  k_count<<<(ET + 255) / 256, 256, 0, stream>>>(ei, counts);
  k_scan<<<1, 1024, 0, stream>>>(counts, offs, cursor);
  k_fill<<<(ET + 255) / 256, 256, 0, stream>>>(ei, cursor, srcs);

  // running h buffer lives in d_out: agg1 writes it; gemm2/agg2 read + overwrite
  // in place (same-index per-thread RW); agg3 writes the final output.
  dim3 g12((NN + 127) / 128, 8, 2);
  gemm_xlr<<<g12, 256, 0, stream>>>(x, W1l, W1r, xl, xr, NN, 1024);
  gat_agg<8><<<(NN + 3) / 4, 256, 0, stream>>>(xl, xr, offs, srcs, att1, b1, x, out, 1);

  gemm_xlr<<<g12, 256, 0, stream>>>(out, W2l, W2r, xl, xr, NN, 1024);
  gat_agg<8><<<(NN + 3) / 4, 256, 0, stream>>>(xl, xr, offs, srcs, att2, b2, out, out, 1);

  dim3 g3((NN + 127) / 128, 4, 2);
  gemm_xlr<<<g3, 256, 0, stream>>>(out, W3l, W3r, xl, xr, NN, 512);
  gat_agg<4><<<(NN + 3) / 4, 256, 0, stream>>>(xl, xr, offs, srcs, att3, b3, out, out, 0);
}

// Round 3
// 544.389 us; speedup vs baseline: 1.5519x; 1.5519x over previous
//
#include <hip/hip_runtime.h>

#define NN 50000
#define DD 128
#define EE 100000
#define ET (EE + NN)

typedef __attribute__((ext_vector_type(4))) float f32x4;
typedef __attribute__((ext_vector_type(2))) float f32x2;
typedef __attribute__((ext_vector_type(8))) short bf16x8;
typedef __attribute__((ext_vector_type(4))) unsigned short u16x4;

static __device__ __forceinline__ unsigned short f2bf(float f) {
  union { float f; unsigned int u; } v; v.f = f;
  unsigned int r = (v.u + 0x7FFFu + ((v.u >> 16) & 1u)) >> 16;
  return (unsigned short)r;
}
static __device__ __forceinline__ float bf2f(unsigned short s) {
  union { unsigned int u; float f; } v; v.u = ((unsigned int)s) << 16;
  return v.f;
}

// ---------------- CSR build (edge_index int32: row0=src, row1=dst) ----------------
__global__ void k_count(const int* __restrict__ ei, int* __restrict__ counts) {
  int i = blockIdx.x * blockDim.x + threadIdx.x;
  if (i >= ET) return;
  int dst = (i < EE) ? ei[EE + i] : (i - EE);
  if (dst < 0 || dst >= NN) return;
  atomicAdd(&counts[dst], 1);
}

__global__ __launch_bounds__(1024) void k_scan(const int* __restrict__ counts,
                                               int* __restrict__ offs,
                                               int* __restrict__ cursor) {
  __shared__ int buf[1024];
  const int tid = threadIdx.x;
  int carry = 0;
  for (int base = 0; base < NN; base += 4096) {
    int i0 = base + tid * 4;
    int v[4];
#pragma unroll
    for (int q = 0; q < 4; ++q) { int i = i0 + q; v[q] = (i < NN) ? counts[i] : 0; }
    int s = v[0] + v[1] + v[2] + v[3];
    buf[tid] = s;
    __syncthreads();
    for (int off = 1; off < 1024; off <<= 1) {
      int t = (tid >= off) ? buf[tid - off] : 0;
      __syncthreads();
      buf[tid] += t;
      __syncthreads();
    }
    int excl = carry + buf[tid] - s;
    int tot = buf[1023];
#pragma unroll
    for (int q = 0; q < 4; ++q) {
      int i = i0 + q;
      if (i < NN) { offs[i] = excl; cursor[i] = excl; }
      excl += v[q];
    }
    carry += tot;
    __syncthreads();
  }
  if (tid == 0) offs[NN] = carry;
}

__global__ void k_fill(const int* __restrict__ ei, int* __restrict__ cursor,
                       int* __restrict__ srcs) {
  int i = blockIdx.x * blockDim.x + threadIdx.x;
  if (i >= ET) return;
  int src, dst;
  if (i < EE) { src = ei[i]; dst = ei[EE + i]; }
  else { src = dst = i - EE; }
  if (dst < 0 || dst >= NN) return;
  if (src < 0 || src >= NN) src = dst;
  int pos = atomicAdd(&cursor[dst], 1);
  if (pos >= 0 && pos < ET) srcs[pos] = src;
}

// ---------------- weight transpose: W[128,Nout] f32 -> WT[Nout][128] bf16 ----------------
__global__ void k_wT(const float* __restrict__ W, unsigned short* __restrict__ WT, int Nout) {
  int i = blockIdx.x * blockDim.x + threadIdx.x;
  int total = Nout * DD;
  if (i >= total) return;
  int n = i >> 7, k = i & 127;
  WT[i] = f2bf(W[(size_t)k * Nout + n]);
}

// ---------------- f32 -> bf16 convert ----------------
__global__ void k_cvt(const float* __restrict__ in, unsigned short* __restrict__ out, int total4) {
  int i = blockIdx.x * blockDim.x + threadIdx.x;
  if (i >= total4) return;
  f32x4 v = *(const f32x4*)(in + (size_t)i * 4);
  u16x4 w;
  w.x = f2bf(v.x); w.y = f2bf(v.y); w.z = f2bf(v.z); w.w = f2bf(v.w);
  *(u16x4*)(out + (size_t)i * 4) = w;
}

// ---------------- GEMM: C(bf16)[M,Nout] = A(bf16)[M,128] @ WT(bf16)[2][Nout][128]^T ----------
// 1-D grid: flat = x*ny + c, c = (y<<1)|z  -> blocks sharing an A-tile are consecutive.
__global__ __launch_bounds__(256) void gemm_bt(
    const unsigned short* __restrict__ A, const unsigned short* __restrict__ WT,
    unsigned short* __restrict__ Cl, unsigned short* __restrict__ Cr,
    int M, int Nout, int lgny) {
  const int f = blockIdx.x;
  const int c = f & ((1 << lgny) - 1);
  const int x = f >> lgny;
  const int z = c & 1, y = c >> 1;
  const int m0 = x * 128, n0 = y * 128;
  unsigned short* C = z ? Cr : Cl;
  const unsigned short* BT = WT + (size_t)z * Nout * DD;

  __shared__ unsigned short As[128 * 128];
  __shared__ unsigned short Bs[128 * 128];
  const int tid = threadIdx.x;
  const int wave = tid >> 6, lane = tid & 63;
  const int hi = lane >> 4, lr = lane & 15;

  // stage: LDS linear [row][16B-slot]; source 16B-slot pre-XOR'd with row&7
#pragma unroll
  for (int i = 0; i < 8; ++i) {
    int row = i * 16 + wave * 4 + hi;
    int c16 = lr ^ (row & 7);
    const unsigned short* ga = A + (size_t)(m0 + row) * DD + c16 * 8;
    __builtin_amdgcn_global_load_lds((const __attribute__((address_space(1))) void*)ga,
        (__attribute__((address_space(3))) void*)(As + i * 2048 + wave * 512), 16, 0, 0);
    const unsigned short* gb = BT + (size_t)(n0 + row) * DD + c16 * 8;
    __builtin_amdgcn_global_load_lds((const __attribute__((address_space(1))) void*)gb,
        (__attribute__((address_space(3))) void*)(Bs + i * 2048 + wave * 512), 16, 0, 0);
  }
  __syncthreads();

  const int wr = (wave >> 1) * 64, wc = (wave & 1) * 64;
  f32x4 acc[4][4];
#pragma unroll
  for (int i = 0; i < 4; ++i)
#pragma unroll
    for (int j = 0; j < 4; ++j) acc[i][j] = (f32x4){0.f, 0.f, 0.f, 0.f};

#pragma unroll
  for (int k0 = 0; k0 < 128; k0 += 32) {
    const int ck = (k0 >> 3) + hi;
    bf16x8 af[4], bfr[4];
#pragma unroll
    for (int mi = 0; mi < 4; ++mi) {
      int r = wr + mi * 16 + lr;
      af[mi] = *(const bf16x8*)&As[r * 128 + ((ck ^ (r & 7)) << 3)];
    }
#pragma unroll
    for (int ni = 0; ni < 4; ++ni) {
      int cc = wc + ni * 16 + lr;
      bfr[ni] = *(const bf16x8*)&Bs[cc * 128 + ((ck ^ (cc & 7)) << 3)];
    }
#pragma unroll
    for (int mi = 0; mi < 4; ++mi)
#pragma unroll
      for (int ni = 0; ni < 4; ++ni)
        acc[mi][ni] = __builtin_amdgcn_mfma_f32_16x16x32_bf16(af[mi], bfr[ni], acc[mi][ni], 0, 0, 0);
  }

  // C/D layout: col = lane&15, row = (lane>>4)*4 + reg
#pragma unroll
  for (int mi = 0; mi < 4; ++mi) {
#pragma unroll
    for (int ni = 0; ni < 4; ++ni) {
      int col = n0 + wc + ni * 16 + lr;
#pragma unroll
      for (int j = 0; j < 4; ++j) {
        int row = m0 + wr + mi * 16 + (hi << 2) + j;
        if (row < M) C[(size_t)row * Nout + col] = f2bf(acc[mi][ni][j]);
      }
    }
  }
}

// ---------------- fused score + online softmax + aggregation ----------------
// one WAVE per dst node; wave handles ALL heads; lane handles 2 channels.
template <int H>
__global__ __launch_bounds__(256) void gat_agg(
    const unsigned short* __restrict__ xl, const unsigned short* __restrict__ xr,
    const int* __restrict__ offs, const int* __restrict__ srcs,
    const float* __restrict__ att, const float* __restrict__ bias,
    const float* __restrict__ resid, float* __restrict__ out,
    unsigned short* __restrict__ hbf, int do_elu) {
  const int wave = threadIdx.x >> 6, lane = threadIdx.x & 63;
  const int n = blockIdx.x * 4 + wave;
  if (n >= NN) return;
  const int c0 = lane << 1;

  float xr0[H], xr1[H], a0[H], a1[H];
  float acc0[H], acc1[H], mx[H], dn[H];
#pragma unroll
  for (int h = 0; h < H; ++h) {
    unsigned int u = *(const unsigned int*)(xr + ((size_t)n * H + h) * DD + c0);
    xr0[h] = bf2f((unsigned short)(u & 0xFFFFu));
    xr1[h] = bf2f((unsigned short)(u >> 16));
    a0[h] = att[h * DD + c0];
    a1[h] = att[h * DD + c0 + 1];
    acc0[h] = 0.f; acc1[h] = 0.f; mx[h] = -1e30f; dn[h] = 0.f;
  }

  const int e0 = offs[n], e1 = offs[n + 1];
  for (int j = e0; j < e1; ++j) {
    int s = srcs[j];
#pragma unroll
    for (int h = 0; h < H; ++h) {
      unsigned int u = *(const unsigned int*)(xl + ((size_t)s * H + h) * DD + c0);
      float x0 = bf2f((unsigned short)(u & 0xFFFFu));
      float x1 = bf2f((unsigned short)(u >> 16));
      float z0 = x0 + xr0[h]; z0 = (z0 > 0.f) ? z0 : 0.2f * z0;
      float z1 = x1 + xr1[h]; z1 = (z1 > 0.f) ? z1 : 0.2f * z1;
      float p = z0 * a0[h] + z1 * a1[h];
#pragma unroll
      for (int m = 1; m < 64; m <<= 1) p += __shfl_xor(p, m, 64);
      float mnew = fmaxf(mx[h], p);
      float sc = __expf(mx[h] - mnew);
      float w = __expf(p - mnew);
      acc0[h] = acc0[h] * sc + w * x0;
      acc1[h] = acc1[h] * sc + w * x1;
      dn[h] = dn[h] * sc + w;
      mx[h] = mnew;
    }
  }

  float s0 = 0.f, s1 = 0.f;
#pragma unroll
  for (int h = 0; h < H; ++h) {
    float inv = 1.f / dn[h];
    s0 += acc0[h] * inv;
    s1 += acc1[h] * inv;
  }
  const float invH = 1.f / (float)H;
  float o0 = s0 * invH + bias[c0] + resid[(size_t)n * DD + c0];
  float o1 = s1 * invH + bias[c0 + 1] + resid[(size_t)n * DD + c0 + 1];
  if (do_elu) {
    o0 = (o0 > 0.f) ? o0 : expm1f(o0);
    o1 = (o1 > 0.f) ? o1 : expm1f(o1);
  }
  f32x2 o; o.x = o0; o.y = o1;
  *(f32x2*)(out + (size_t)n * DD + c0) = o;
  if (hbf) {
    unsigned int pk = (unsigned int)f2bf(o0) | ((unsigned int)f2bf(o1) << 16);
    *(unsigned int*)(hbf + (size_t)n * DD + c0) = pk;
  }
}

extern "C" void kernel_launch(void* const* d_in, const int* in_sizes, int n_in,
                              void* d_out, int out_size, void* d_ws, size_t ws_size,
                              hipStream_t stream) {
  const float* x = (const float*)d_in[0];
  const int* ei = (const int*)d_in[1];
  const float* W1l = (const float*)d_in[2];
  const float* W1r = (const float*)d_in[3];
  const float* att1 = (const float*)d_in[4];
  const float* b1 = (const float*)d_in[5];
  const float* W2l = (const float*)d_in[6];
  const float* W2r = (const float*)d_in[7];
  const float* att2 = (const float*)d_in[8];
  const float* b2 = (const float*)d_in[9];
  const float* W3l = (const float*)d_in[10];
  const float* W3r = (const float*)d_in[11];
  const float* att3 = (const float*)d_in[12];
  const float* b3 = (const float*)d_in[13];
  float* out = (float*)d_out;

  char* p = (char*)d_ws;
  auto carve = [&](size_t bytes) {
    char* r = p;
    p += (bytes + 255) & ~(size_t)255;
    return r;
  };
  unsigned short* xl = (unsigned short*)carve((size_t)NN * 1024 * 2);
  unsigned short* xr = (unsigned short*)carve((size_t)NN * 1024 * 2);
  unsigned short* abf = (unsigned short*)carve((size_t)NN * DD * 2);   // bf16 A for each layer
  unsigned short* wt1 = (unsigned short*)carve((size_t)2 * 1024 * DD * 2);
  unsigned short* wt2 = (unsigned short*)carve((size_t)2 * 1024 * DD * 2);
  unsigned short* wt3 = (unsigned short*)carve((size_t)2 * 512 * DD * 2);
  int* counts = (int*)carve((size_t)NN * 4);
  int* offs = (int*)carve(((size_t)NN + 1) * 4);
  int* cursor = (int*)carve((size_t)NN * 4);
  int* srcs = (int*)carve((size_t)ET * 4);
  size_t needed = (size_t)(p - (char*)d_ws);
  if (needed > ws_size) return;  // graceful fail instead of OOB fault

  // CSR
  hipMemsetAsync(counts, 0, (size_t)NN * 4, stream);
  k_count<<<(ET + 255) / 256, 256, 0, stream>>>(ei, counts);
  k_scan<<<1, 1024, 0, stream>>>(counts, offs, cursor);
  k_fill<<<(ET + 255) / 256, 256, 0, stream>>>(ei, cursor, srcs);

  // weights -> bf16 transposed [Nout][128]
  k_wT<<<(1024 * DD + 255) / 256, 256, 0, stream>>>(W1l, wt1, 1024);
  k_wT<<<(1024 * DD + 255) / 256, 256, 0, stream>>>(W1r, wt1 + (size_t)1024 * DD, 1024);
  k_wT<<<(1024 * DD + 255) / 256, 256, 0, stream>>>(W2l, wt2, 1024);
  k_wT<<<(1024 * DD + 255) / 256, 256, 0, stream>>>(W2r, wt2 + (size_t)1024 * DD, 1024);
  k_wT<<<(512 * DD + 255) / 256, 256, 0, stream>>>(W3l, wt3, 512);
  k_wT<<<(512 * DD + 255) / 256, 256, 0, stream>>>(W3r, wt3 + (size_t)512 * DD, 512);

  // x -> bf16
  k_cvt<<<((NN * DD / 4) + 255) / 256, 256, 0, stream>>>(x, abf, NN * DD / 4);

  const int gx = (NN + 127) / 128;  // 391
  // layer 1
  gemm_bt<<<gx * 16, 256, 0, stream>>>(abf, wt1, xl, xr, NN, 1024, 4);
  gat_agg<8><<<(NN + 3) / 4, 256, 0, stream>>>(xl, xr, offs, srcs, att1, b1, x, out, abf, 1);
  // layer 2
  gemm_bt<<<gx * 16, 256, 0, stream>>>(abf, wt2, xl, xr, NN, 1024, 4);
  gat_agg<8><<<(NN + 3) / 4, 256, 0, stream>>>(xl, xr, offs, srcs, att2, b2, out, out, abf, 1);
  // layer 3
  gemm_bt<<<gx * 8, 256, 0, stream>>>(abf, wt3, xl, xr, NN, 512, 3);
  gat_agg<4><<<(NN + 3) / 4, 256, 0, stream>>>(xl, xr, offs, srcs, att3, b3, out, out, nullptr, 0);
}

// Round 4
// 544.006 us; speedup vs baseline: 1.5530x; 1.0007x over previous
//
#include <hip/hip_runtime.h>

#define NN 50000
#define DD 128
#define EE 100000
#define ET (EE + NN)

typedef __attribute__((ext_vector_type(4))) float f32x4;
typedef __attribute__((ext_vector_type(2))) float f32x2;
typedef __attribute__((ext_vector_type(8))) short bf16x8;
typedef __attribute__((ext_vector_type(4))) unsigned short u16x4;
typedef __attribute__((ext_vector_type(4))) unsigned int u32x4;

static __device__ __forceinline__ unsigned short f2bf(float f) {
  union { float f; unsigned int u; } v; v.f = f;
  unsigned int r = (v.u + 0x7FFFu + ((v.u >> 16) & 1u)) >> 16;
  return (unsigned short)r;
}
static __device__ __forceinline__ float bflo(unsigned int u) {
  union { unsigned int u; float f; } v; v.u = u << 16; return v.f;
}
static __device__ __forceinline__ float bfhi(unsigned int u) {
  union { unsigned int u; float f; } v; v.u = u & 0xffff0000u; return v.f;
}

// ---------------- CSR build (edge_index int32: row0=src, row1=dst) ----------------
__global__ void k_count(const int* __restrict__ ei, int* __restrict__ counts) {
  int i = blockIdx.x * blockDim.x + threadIdx.x;
  if (i >= ET) return;
  int dst = (i < EE) ? ei[EE + i] : (i - EE);
  if (dst < 0 || dst >= NN) return;
  atomicAdd(&counts[dst], 1);
}

__global__ __launch_bounds__(1024) void k_scan(const int* __restrict__ counts,
                                               int* __restrict__ offs,
                                               int* __restrict__ cursor) {
  __shared__ int buf[1024];
  const int tid = threadIdx.x;
  int carry = 0;
  for (int base = 0; base < NN; base += 4096) {
    int i0 = base + tid * 4;
    int v[4];
#pragma unroll
    for (int q = 0; q < 4; ++q) { int i = i0 + q; v[q] = (i < NN) ? counts[i] : 0; }
    int s = v[0] + v[1] + v[2] + v[3];
    buf[tid] = s;
    __syncthreads();
    for (int off = 1; off < 1024; off <<= 1) {
      int t = (tid >= off) ? buf[tid - off] : 0;
      __syncthreads();
      buf[tid] += t;
      __syncthreads();
    }
    int excl = carry + buf[tid] - s;
    int tot = buf[1023];
#pragma unroll
    for (int q = 0; q < 4; ++q) {
      int i = i0 + q;
      if (i < NN) { offs[i] = excl; cursor[i] = excl; }
      excl += v[q];
    }
    carry += tot;
    __syncthreads();
  }
  if (tid == 0) offs[NN] = carry;
}

__global__ void k_fill(const int* __restrict__ ei, int* __restrict__ cursor,
                       int* __restrict__ srcs) {
  int i = blockIdx.x * blockDim.x + threadIdx.x;
  if (i >= ET) return;
  int src, dst;
  if (i < EE) { src = ei[i]; dst = ei[EE + i]; }
  else { src = dst = i - EE; }
  if (dst < 0 || dst >= NN) return;
  if (src < 0 || src >= NN) src = dst;
  int pos = atomicAdd(&cursor[dst], 1);
  if (pos >= 0 && pos < ET) srcs[pos] = src;
}

// ---------------- weight transpose: W[128,Nout] f32 -> WT[Nout][128] bf16 ----------------
__global__ void k_wT(const float* __restrict__ W, unsigned short* __restrict__ WT, int Nout) {
  int i = blockIdx.x * blockDim.x + threadIdx.x;
  int total = Nout * DD;
  if (i >= total) return;
  int n = i >> 7, k = i & 127;
  WT[i] = f2bf(W[(size_t)k * Nout + n]);
}

// ---------------- f32 -> bf16 convert ----------------
__global__ void k_cvt(const float* __restrict__ in, unsigned short* __restrict__ out, int total4) {
  int i = blockIdx.x * blockDim.x + threadIdx.x;
  if (i >= total4) return;
  f32x4 v = *(const f32x4*)(in + (size_t)i * 4);
  u16x4 w;
  w.x = f2bf(v.x); w.y = f2bf(v.y); w.z = f2bf(v.z); w.w = f2bf(v.w);
  *(u16x4*)(out + (size_t)i * 4) = w;
}

// ---------------- att scale by log2(e) ----------------
__global__ void k_atts(const float* __restrict__ a, float* __restrict__ o, int total) {
  int i = blockIdx.x * blockDim.x + threadIdx.x;
  if (i >= total) return;
  o[i] = a[i] * 1.4426950408889634f;
}

// ---------------- GEMM: C(bf16)[M,Nout] = A(bf16)[M,128] @ WT(bf16)[2][Nout][128]^T ----------
__global__ __launch_bounds__(256) void gemm_bt(
    const unsigned short* __restrict__ A, const unsigned short* __restrict__ WT,
    unsigned short* __restrict__ Cl, unsigned short* __restrict__ Cr,
    int M, int Nout, int lgny) {
  const int f = blockIdx.x;
  const int c = f & ((1 << lgny) - 1);
  const int x = f >> lgny;
  const int z = c & 1, y = c >> 1;
  const int m0 = x * 128, n0 = y * 128;
  unsigned short* C = z ? Cr : Cl;
  const unsigned short* BT = WT + (size_t)z * Nout * DD;

  __shared__ unsigned short As[128 * 128];
  __shared__ unsigned short Bs[128 * 128];
  const int tid = threadIdx.x;
  const int wave = tid >> 6, lane = tid & 63;
  const int hi = lane >> 4, lr = lane & 15;

#pragma unroll
  for (int i = 0; i < 8; ++i) {
    int row = i * 16 + wave * 4 + hi;
    int c16 = lr ^ (row & 7);
    const unsigned short* ga = A + (size_t)(m0 + row) * DD + c16 * 8;
    __builtin_amdgcn_global_load_lds((const __attribute__((address_space(1))) void*)ga,
        (__attribute__((address_space(3))) void*)(As + i * 2048 + wave * 512), 16, 0, 0);
    const unsigned short* gb = BT + (size_t)(n0 + row) * DD + c16 * 8;
    __builtin_amdgcn_global_load_lds((const __attribute__((address_space(1))) void*)gb,
        (__attribute__((address_space(3))) void*)(Bs + i * 2048 + wave * 512), 16, 0, 0);
  }
  __syncthreads();

  const int wr = (wave >> 1) * 64, wc = (wave & 1) * 64;
  f32x4 acc[4][4];
#pragma unroll
  for (int i = 0; i < 4; ++i)
#pragma unroll
    for (int j = 0; j < 4; ++j) acc[i][j] = (f32x4){0.f, 0.f, 0.f, 0.f};

#pragma unroll
  for (int k0 = 0; k0 < 128; k0 += 32) {
    const int ck = (k0 >> 3) + hi;
    bf16x8 af[4], bfr[4];
#pragma unroll
    for (int mi = 0; mi < 4; ++mi) {
      int r = wr + mi * 16 + lr;
      af[mi] = *(const bf16x8*)&As[r * 128 + ((ck ^ (r & 7)) << 3)];
    }
#pragma unroll
    for (int ni = 0; ni < 4; ++ni) {
      int cc = wc + ni * 16 + lr;
      bfr[ni] = *(const bf16x8*)&Bs[cc * 128 + ((ck ^ (cc & 7)) << 3)];
    }
#pragma unroll
    for (int mi = 0; mi < 4; ++mi)
#pragma unroll
      for (int ni = 0; ni < 4; ++ni)
        acc[mi][ni] = __builtin_amdgcn_mfma_f32_16x16x32_bf16(af[mi], bfr[ni], acc[mi][ni], 0, 0, 0);
  }

#pragma unroll
  for (int mi = 0; mi < 4; ++mi) {
#pragma unroll
    for (int ni = 0; ni < 4; ++ni) {
      int col = n0 + wc + ni * 16 + lr;
#pragma unroll
      for (int j = 0; j < 4; ++j) {
        int row = m0 + wr + mi * 16 + (hi << 2) + j;
        if (row < M) C[(size_t)row * Nout + col] = f2bf(acc[mi][ni][j]);
      }
    }
  }
}

// ---------------- fused score + softmax + aggregation, head-parallel ----------------
// one WAVE per node. lane l -> head l/LPH, channels (l%LPH)*CPL .. +CPL  (== lane*CPL).
template <int H>
__global__ __launch_bounds__(256) void gat_agg2(
    const unsigned short* __restrict__ xl, const unsigned short* __restrict__ xr,
    const int* __restrict__ offs, const int* __restrict__ srcs,
    const float* __restrict__ att_s,  // att * log2(e), [H][128]
    const float* __restrict__ bias,
    const float* __restrict__ resid, float* __restrict__ out,
    unsigned short* __restrict__ hbf, int do_elu) {
  constexpr int LPH = 64 / H;    // lanes per head
  constexpr int CPL = 2 * H;     // channels per lane
  constexpr int NW = H;          // u32 words per lane
  constexpr int ROW = H * DD;    // halfwords per row
  const int wave = threadIdx.x >> 6, lane = threadIdx.x & 63;
  const int n = blockIdx.x * 4 + wave;
  if (n >= NN) return;
  const int cb = lane * CPL;     // halfword offset within row

  // xr row + scaled att
  float xrv[CPL], av[CPL];
  {
    const unsigned int* q = (const unsigned int*)(xr + (size_t)n * ROW + cb);
#pragma unroll
    for (int w = 0; w < NW; ++w) {
      unsigned int u = q[w];
      xrv[2 * w] = bflo(u);
      xrv[2 * w + 1] = bfhi(u);
    }
#pragma unroll
    for (int c = 0; c < CPL; ++c) av[c] = att_s[cb + c];
  }

  float acc[CPL];
#pragma unroll
  for (int c = 0; c < CPL; ++c) acc[c] = 0.f;
  float mx = -1e30f, dn = 0.f;

  const int e0 = offs[n], e1 = offs[n + 1];
  unsigned int cur[NW], nxt[NW];
  {
    int s = srcs[e0];
    const unsigned int* q = (const unsigned int*)(xl + (size_t)s * ROW + cb);
#pragma unroll
    for (int w = 0; w < NW; ++w) cur[w] = q[w];
  }
  for (int j = e0; j < e1; ++j) {
    if (j + 1 < e1) {
      int s2 = srcs[j + 1];
      const unsigned int* q = (const unsigned int*)(xl + (size_t)s2 * ROW + cb);
#pragma unroll
      for (int w = 0; w < NW; ++w) nxt[w] = q[w];
    }
    float xv[CPL];
#pragma unroll
    for (int w = 0; w < NW; ++w) {
      xv[2 * w] = bflo(cur[w]);
      xv[2 * w + 1] = bfhi(cur[w]);
    }
    float p = 0.f;
#pragma unroll
    for (int c = 0; c < CPL; ++c) {
      float z = xv[c] + xrv[c];
      z = fmaxf(z, 0.2f * z);           // leaky_relu (slope<1)
      p = fmaf(z, av[c], p);
    }
#pragma unroll
    for (int m = 1; m < LPH; m <<= 1) p += __shfl_xor(p, m, 64);
    if (__any(p > mx + 11.5f)) {        // defer-max rescale (log2 units)
      float mnew = fmaxf(mx, p);
      float sc = __builtin_amdgcn_exp2f(mx - mnew);
      dn *= sc;
#pragma unroll
      for (int c = 0; c < CPL; ++c) acc[c] *= sc;
      mx = mnew;
    }
    float wt = __builtin_amdgcn_exp2f(p - mx);
    dn += wt;
#pragma unroll
    for (int c = 0; c < CPL; ++c) acc[c] = fmaf(wt, xv[c], acc[c]);
#pragma unroll
    for (int w = 0; w < NW; ++w) cur[w] = nxt[w];
  }

  // per-head normalize + fold head-mean, then butterfly across head groups
  float r[CPL];
  const float inv = (1.f / (float)H) / dn;
#pragma unroll
  for (int c = 0; c < CPL; ++c) r[c] = acc[c] * inv;
#pragma unroll
  for (int m = LPH; m < 64; m <<= 1)
#pragma unroll
    for (int c = 0; c < CPL; ++c) r[c] += __shfl_xor(r[c], m, 64);

  if (lane < LPH) {  // head-0 lanes hold channels cb..cb+CPL (cb = lane*CPL)
    float o[CPL];
#pragma unroll
    for (int c = 0; c < CPL; ++c) {
      o[c] = r[c] + bias[cb + c] + resid[(size_t)n * DD + cb + c];
      if (do_elu) o[c] = (o[c] > 0.f) ? o[c] : expm1f(o[c]);
    }
#pragma unroll
    for (int c = 0; c < CPL; c += 4) {
      f32x4 v; v.x = o[c]; v.y = o[c + 1]; v.z = o[c + 2]; v.w = o[c + 3];
      *(f32x4*)(out + (size_t)n * DD + cb + c) = v;
    }
    if (hbf) {
#pragma unroll
      for (int c = 0; c < CPL; c += 8) {
        u32x4 pk;
#pragma unroll
        for (int q = 0; q < 4; ++q)
          pk[q] = (unsigned int)f2bf(o[c + 2 * q]) | ((unsigned int)f2bf(o[c + 2 * q + 1]) << 16);
        *(u32x4*)(hbf + (size_t)n * DD + cb + c) = pk;
      }
    }
  }
}

extern "C" void kernel_launch(void* const* d_in, const int* in_sizes, int n_in,
                              void* d_out, int out_size, void* d_ws, size_t ws_size,
                              hipStream_t stream) {
  const float* x = (const float*)d_in[0];
  const int* ei = (const int*)d_in[1];
  const float* W1l = (const float*)d_in[2];
  const float* W1r = (const float*)d_in[3];
  const float* att1 = (const float*)d_in[4];
  const float* b1 = (const float*)d_in[5];
  const float* W2l = (const float*)d_in[6];
  const float* W2r = (const float*)d_in[7];
  const float* att2 = (const float*)d_in[8];
  const float* b2 = (const float*)d_in[9];
  const float* W3l = (const float*)d_in[10];
  const float* W3r = (const float*)d_in[11];
  const float* att3 = (const float*)d_in[12];
  const float* b3 = (const float*)d_in[13];
  float* out = (float*)d_out;

  char* p = (char*)d_ws;
  auto carve = [&](size_t bytes) {
    char* r = p;
    p += (bytes + 255) & ~(size_t)255;
    return r;
  };
  unsigned short* xl = (unsigned short*)carve((size_t)NN * 1024 * 2);
  unsigned short* xr = (unsigned short*)carve((size_t)NN * 1024 * 2);
  unsigned short* abf = (unsigned short*)carve((size_t)NN * DD * 2);
  unsigned short* wt1 = (unsigned short*)carve((size_t)2 * 1024 * DD * 2);
  unsigned short* wt2 = (unsigned short*)carve((size_t)2 * 1024 * DD * 2);
  unsigned short* wt3 = (unsigned short*)carve((size_t)2 * 512 * DD * 2);
  float* as1 = (float*)carve((size_t)8 * DD * 4);
  float* as2 = (float*)carve((size_t)8 * DD * 4);
  float* as3 = (float*)carve((size_t)4 * DD * 4);
  int* counts = (int*)carve((size_t)NN * 4);
  int* offs = (int*)carve(((size_t)NN + 1) * 4);
  int* cursor = (int*)carve((size_t)NN * 4);
  int* srcs = (int*)carve((size_t)ET * 4);
  size_t needed = (size_t)(p - (char*)d_ws);
  if (needed > ws_size) return;

  // CSR
  hipMemsetAsync(counts, 0, (size_t)NN * 4, stream);
  k_count<<<(ET + 255) / 256, 256, 0, stream>>>(ei, counts);
  k_scan<<<1, 1024, 0, stream>>>(counts, offs, cursor);
  k_fill<<<(ET + 255) / 256, 256, 0, stream>>>(ei, cursor, srcs);

  // weights -> bf16 transposed; att -> *log2e
  k_wT<<<(1024 * DD + 255) / 256, 256, 0, stream>>>(W1l, wt1, 1024);
  k_wT<<<(1024 * DD + 255) / 256, 256, 0, stream>>>(W1r, wt1 + (size_t)1024 * DD, 1024);
  k_wT<<<(1024 * DD + 255) / 256, 256, 0, stream>>>(W2l, wt2, 1024);
  k_wT<<<(1024 * DD + 255) / 256, 256, 0, stream>>>(W2r, wt2 + (size_t)1024 * DD, 1024);
  k_wT<<<(512 * DD + 255) / 256, 256, 0, stream>>>(W3l, wt3, 512);
  k_wT<<<(512 * DD + 255) / 256, 256, 0, stream>>>(W3r, wt3 + (size_t)512 * DD, 512);
  k_atts<<<4, 256, 0, stream>>>(att1, as1, 8 * DD);
  k_atts<<<4, 256, 0, stream>>>(att2, as2, 8 * DD);
  k_atts<<<2, 256, 0, stream>>>(att3, as3, 4 * DD);

  // x -> bf16
  k_cvt<<<((NN * DD / 4) + 255) / 256, 256, 0, stream>>>(x, abf, NN * DD / 4);

  const int gx = (NN + 127) / 128;
  // layer 1
  gemm_bt<<<gx * 16, 256, 0, stream>>>(abf, wt1, xl, xr, NN, 1024, 4);
  gat_agg2<8><<<(NN + 3) / 4, 256, 0, stream>>>(xl, xr, offs, srcs, as1, b1, x, out, abf, 1);
  // layer 2
  gemm_bt<<<gx * 16, 256, 0, stream>>>(abf, wt2, xl, xr, NN, 1024, 4);
  gat_agg2<8><<<(NN + 3) / 4, 256, 0, stream>>>(xl, xr, offs, srcs, as2, b2, out, out, abf, 1);
  // layer 3
  gemm_bt<<<gx * 8, 256, 0, stream>>>(abf, wt3, xl, xr, NN, 512, 3);
  gat_agg2<4><<<(NN + 3) / 4, 256, 0, stream>>>(xl, xr, offs, srcs, as3, b3, out, out, nullptr, 0);
}

// Round 5
// 492.097 us; speedup vs baseline: 1.7168x; 1.1055x over previous
//
#include <hip/hip_runtime.h>

#define NN 50000
#define DD 128
#define EE 100000
#define ET (EE + NN)

typedef __attribute__((ext_vector_type(4))) float f32x4;
typedef __attribute__((ext_vector_type(8))) short bf16x8;
typedef __attribute__((ext_vector_type(4))) unsigned short u16x4;
typedef __attribute__((ext_vector_type(4))) unsigned int u32x4;

static __device__ __forceinline__ unsigned short f2bf(float f) {
  union { float f; unsigned int u; } v; v.f = f;
  unsigned int r = (v.u + 0x7FFFu + ((v.u >> 16) & 1u)) >> 16;
  return (unsigned short)r;
}
static __device__ __forceinline__ float bflo(unsigned int u) {
  union { unsigned int u; float f; } v; v.u = u << 16; return v.f;
}
static __device__ __forceinline__ float bfhi(unsigned int u) {
  union { unsigned int u; float f; } v; v.u = u & 0xffff0000u; return v.f;
}

// ---------------- fused prep: W transposes, att*log2e, x->bf16, counts=0 ----------------
__global__ __launch_bounds__(256) void k_prep(
    const float* __restrict__ x,
    const float* __restrict__ W1l, const float* __restrict__ W1r,
    const float* __restrict__ W2l, const float* __restrict__ W2r,
    const float* __restrict__ W3l, const float* __restrict__ W3r,
    const float* __restrict__ att1, const float* __restrict__ att2, const float* __restrict__ att3,
    unsigned short* __restrict__ wt1, unsigned short* __restrict__ wt2,
    unsigned short* __restrict__ wt3,
    float* __restrict__ as1, float* __restrict__ as2, float* __restrict__ as3,
    unsigned short* __restrict__ abf, int* __restrict__ counts) {
  const int i = blockIdx.x * 256 + threadIdx.x;
  const float LOG2E = 1.4426950408889634f;
  if (i < 262144) {                      // wt1: [2][1024][128]
    int half = i >> 17, rem = i & 131071;
    int nn = rem >> 7, k = rem & 127;
    const float* W = half ? W1r : W1l;
    wt1[i] = f2bf(W[(size_t)k * 1024 + nn]);
  } else if (i < 524288) {               // wt2
    int local = i - 262144;
    int half = local >> 17, rem = local & 131071;
    int nn = rem >> 7, k = rem & 127;
    const float* W = half ? W2r : W2l;
    wt2[local] = f2bf(W[(size_t)k * 1024 + nn]);
  } else if (i < 655360) {               // wt3: [2][512][128]
    int local = i - 524288;
    int half = local >> 16, rem = local & 65535;
    int nn = rem >> 7, k = rem & 127;
    const float* W = half ? W3r : W3l;
    wt3[local] = f2bf(W[(size_t)k * 512 + nn]);
  } else if (i < 657920) {               // att scales
    int local = i - 655360;
    if (local < 1024) as1[local] = att1[local] * LOG2E;
    else if (local < 2048) as2[local - 1024] = att2[local - 1024] * LOG2E;
    else as3[local - 2048] = att3[local - 2048] * LOG2E;
  } else if (i < 707920) {               // zero counts
    counts[i - 657920] = 0;
  } else if (i < 2307920) {              // x -> bf16 (4 elems/thread)
    int u = i - 707920;
    f32x4 v = *(const f32x4*)(x + (size_t)u * 4);
    u16x4 w;
    w.x = f2bf(v.x); w.y = f2bf(v.y); w.z = f2bf(v.z); w.w = f2bf(v.w);
    *(u16x4*)(abf + (size_t)u * 4) = w;
  }
}

// ---------------- CSR build (edge_index int32: row0=src, row1=dst) ----------------
__global__ void k_count(const int* __restrict__ ei, int* __restrict__ counts) {
  int i = blockIdx.x * blockDim.x + threadIdx.x;
  if (i >= ET) return;
  int dst = (i < EE) ? ei[EE + i] : (i - EE);
  if (dst < 0 || dst >= NN) return;
  atomicAdd(&counts[dst], 1);
}

__global__ __launch_bounds__(1024) void k_scan(const int* __restrict__ counts,
                                               int* __restrict__ offs,
                                               int* __restrict__ cursor) {
  __shared__ int wsum[16];
  __shared__ int wpre[16];
  __shared__ int wtot;
  const int tid = threadIdx.x;
  const int wv = tid >> 6, lane = tid & 63;
  int carry = 0;
  for (int base = 0; base < NN; base += 4096) {
    int i0 = base + tid * 4;
    int v[4];
#pragma unroll
    for (int q = 0; q < 4; ++q) { int i = i0 + q; v[q] = (i < NN) ? counts[i] : 0; }
    int s = v[0] + v[1] + v[2] + v[3];
    int sc = s;  // inclusive wave scan
#pragma unroll
    for (int m = 1; m < 64; m <<= 1) {
      int t = __shfl_up(sc, m, 64);
      if (lane >= m) sc += t;
    }
    if (lane == 63) wsum[wv] = sc;
    __syncthreads();
    if (tid < 16) {
      int t = wsum[tid];
      int scc = t;
#pragma unroll
      for (int m = 1; m < 16; m <<= 1) {
        int u = __shfl_up(scc, m, 64);
        if (tid >= m) scc += u;
      }
      wpre[tid] = scc - t;
      if (tid == 15) wtot = scc;
    }
    __syncthreads();
    int excl = carry + wpre[wv] + (sc - s);
#pragma unroll
    for (int q = 0; q < 4; ++q) {
      int i = i0 + q;
      if (i < NN) { offs[i] = excl; cursor[i] = excl; }
      excl += v[q];
    }
    carry += wtot;
    __syncthreads();
  }
  if (tid == 0) offs[NN] = carry;
}

__global__ void k_fill(const int* __restrict__ ei, int* __restrict__ cursor,
                       int* __restrict__ srcs) {
  int i = blockIdx.x * blockDim.x + threadIdx.x;
  if (i >= ET) return;
  int src, dst;
  if (i < EE) { src = ei[i]; dst = ei[EE + i]; }
  else { src = dst = i - EE; }
  if (dst < 0 || dst >= NN) return;
  if (src < 0 || src >= NN) src = dst;
  int pos = atomicAdd(&cursor[dst], 1);
  if (pos >= 0 && pos < ET) srcs[pos] = src;
}

// ---------------- GEMM: C(bf16)[M,Nout] = A(bf16)[M,128] @ WT(bf16)[2][Nout][128]^T ----------
__global__ __launch_bounds__(256) void gemm_bt(
    const unsigned short* __restrict__ A, const unsigned short* __restrict__ WT,
    unsigned short* __restrict__ Cl, unsigned short* __restrict__ Cr,
    int M, int Nout, int lgny) {
  const int f = blockIdx.x;
  const int c = f & ((1 << lgny) - 1);
  const int x = f >> lgny;
  const int z = c & 1, y = c >> 1;
  const int m0 = x * 128, n0 = y * 128;
  unsigned short* C = z ? Cr : Cl;
  const unsigned short* BT = WT + (size_t)z * Nout * DD;

  __shared__ unsigned short As[128 * 128];
  __shared__ unsigned short Bs[128 * 128];
  const int tid = threadIdx.x;
  const int wave = tid >> 6, lane = tid & 63;
  const int hi = lane >> 4, lr = lane & 15;

#pragma unroll
  for (int i = 0; i < 8; ++i) {
    int row = i * 16 + wave * 4 + hi;
    int c16 = lr ^ (row & 7);
    const unsigned short* ga = A + (size_t)(m0 + row) * DD + c16 * 8;
    __builtin_amdgcn_global_load_lds((const __attribute__((address_space(1))) void*)ga,
        (__attribute__((address_space(3))) void*)(As + i * 2048 + wave * 512), 16, 0, 0);
    const unsigned short* gb = BT + (size_t)(n0 + row) * DD + c16 * 8;
    __builtin_amdgcn_global_load_lds((const __attribute__((address_space(1))) void*)gb,
        (__attribute__((address_space(3))) void*)(Bs + i * 2048 + wave * 512), 16, 0, 0);
  }
  __syncthreads();

  const int wr = (wave >> 1) * 64, wc = (wave & 1) * 64;
  f32x4 acc[4][4];
#pragma unroll
  for (int i = 0; i < 4; ++i)
#pragma unroll
    for (int j = 0; j < 4; ++j) acc[i][j] = (f32x4){0.f, 0.f, 0.f, 0.f};

#pragma unroll
  for (int k0 = 0; k0 < 128; k0 += 32) {
    const int ck = (k0 >> 3) + hi;
    bf16x8 af[4], bfr[4];
#pragma unroll
    for (int mi = 0; mi < 4; ++mi) {
      int r = wr + mi * 16 + lr;
      af[mi] = *(const bf16x8*)&As[r * 128 + ((ck ^ (r & 7)) << 3)];
    }
#pragma unroll
    for (int ni = 0; ni < 4; ++ni) {
      int cc = wc + ni * 16 + lr;
      bfr[ni] = *(const bf16x8*)&Bs[cc * 128 + ((ck ^ (cc & 7)) << 3)];
    }
#pragma unroll
    for (int mi = 0; mi < 4; ++mi)
#pragma unroll
      for (int ni = 0; ni < 4; ++ni)
        acc[mi][ni] = __builtin_amdgcn_mfma_f32_16x16x32_bf16(af[mi], bfr[ni], acc[mi][ni], 0, 0, 0);
  }

#pragma unroll
  for (int mi = 0; mi < 4; ++mi) {
#pragma unroll
    for (int ni = 0; ni < 4; ++ni) {
      int col = n0 + wc + ni * 16 + lr;
#pragma unroll
      for (int j = 0; j < 4; ++j) {
        int row = m0 + wr + mi * 16 + (hi << 2) + j;
        if (row < M) C[(size_t)row * Nout + col] = f2bf(acc[mi][ni][j]);
      }
    }
  }
}

// ---------------- fused score + softmax + aggregation, batched gathers ----------------
// one WAVE per node; lane l -> head l/LPH, channels lane*CPL..+CPL; 4-edge batches.
template <int H>
__global__ __launch_bounds__(256) void gat_agg3(
    const unsigned short* __restrict__ xl, const unsigned short* __restrict__ xr,
    const int* __restrict__ offs, const int* __restrict__ srcs,
    const float* __restrict__ att_s,  // att * log2(e), [H][128]
    const float* __restrict__ bias,
    const float* __restrict__ resid, float* __restrict__ out,
    unsigned short* __restrict__ hbf, int do_elu) {
  constexpr int LPH = 64 / H;
  constexpr int CPL = 2 * H;
  constexpr int NW = H;
  constexpr int ROW = H * DD;
  const int wave = threadIdx.x >> 6, lane = threadIdx.x & 63;
  const int n = blockIdx.x * 4 + wave;
  if (n >= NN) return;
  const int cb = lane * CPL;

  float xrv[CPL], av[CPL];
  {
    const unsigned int* q = (const unsigned int*)(xr + (size_t)n * ROW + cb);
#pragma unroll
    for (int w = 0; w < NW; ++w) {
      unsigned int u = q[w];
      xrv[2 * w] = bflo(u);
      xrv[2 * w + 1] = bfhi(u);
    }
#pragma unroll
    for (int c = 0; c < CPL; ++c) av[c] = att_s[cb + c];
  }

  float acc[CPL];
#pragma unroll
  for (int c = 0; c < CPL; ++c) acc[c] = 0.f;
  float mx = -1e30f, dn = 0.f;

  const int e0 = offs[n], e1 = offs[n + 1];
  for (int j = e0; j < e1; j += 4) {
    const int B = (e1 - j < 4) ? (e1 - j) : 4;
    unsigned int rows[4][NW];
#pragma unroll
    for (int b = 0; b < 4; ++b) {
      if (b < B) {
        int s = srcs[j + b];
        const unsigned int* qq = (const unsigned int*)(xl + (size_t)s * ROW + cb);
#pragma unroll
        for (int w = 0; w < NW; ++w) rows[b][w] = qq[w];
      }
    }
    float p[4];
#pragma unroll
    for (int b = 0; b < 4; ++b) {
      float pp = -1e30f;
      if (b < B) {
        pp = 0.f;
#pragma unroll
        for (int w = 0; w < NW; ++w) {
          float x0 = bflo(rows[b][w]), x1 = bfhi(rows[b][w]);
          float z0 = x0 + xrv[2 * w]; z0 = fmaxf(z0, 0.2f * z0);
          float z1 = x1 + xrv[2 * w + 1]; z1 = fmaxf(z1, 0.2f * z1);
          pp = fmaf(z0, av[2 * w], pp);
          pp = fmaf(z1, av[2 * w + 1], pp);
        }
#pragma unroll
        for (int m = 1; m < LPH; m <<= 1) pp += __shfl_xor(pp, m, 64);
      }
      p[b] = pp;
    }
    float pm = fmaxf(fmaxf(p[0], p[1]), fmaxf(p[2], p[3]));
    if (__any(pm > mx + 11.5f)) {        // defer-max rescale (log2 units)
      float mnew = fmaxf(mx, pm);
      float sc = __builtin_amdgcn_exp2f(mx - mnew);
      dn *= sc;
#pragma unroll
      for (int c = 0; c < CPL; ++c) acc[c] *= sc;
      mx = mnew;
    }
#pragma unroll
    for (int b = 0; b < 4; ++b) {
      if (b < B) {
        float wt = __builtin_amdgcn_exp2f(p[b] - mx);
        dn += wt;
#pragma unroll
        for (int w = 0; w < NW; ++w) {
          acc[2 * w] = fmaf(wt, bflo(rows[b][w]), acc[2 * w]);
          acc[2 * w + 1] = fmaf(wt, bfhi(rows[b][w]), acc[2 * w + 1]);
        }
      }
    }
  }

  // per-head normalize + fold head-mean, then butterfly across head groups
  float r[CPL];
  const float inv = (1.f / (float)H) / dn;
#pragma unroll
  for (int c = 0; c < CPL; ++c) r[c] = acc[c] * inv;
#pragma unroll
  for (int m = LPH; m < 64; m <<= 1)
#pragma unroll
    for (int c = 0; c < CPL; ++c) r[c] += __shfl_xor(r[c], m, 64);

  if (lane < LPH) {  // head-0 lanes hold channels cb..cb+CPL
    float o[CPL];
#pragma unroll
    for (int c = 0; c < CPL; ++c) {
      o[c] = r[c] + bias[cb + c] + resid[(size_t)n * DD + cb + c];
      if (do_elu && o[c] < 0.f)
        o[c] = __builtin_amdgcn_exp2f(o[c] * 1.4426950408889634f) - 1.f;
    }
#pragma unroll
    for (int c = 0; c < CPL; c += 4) {
      f32x4 v; v.x = o[c]; v.y = o[c + 1]; v.z = o[c + 2]; v.w = o[c + 3];
      *(f32x4*)(out + (size_t)n * DD + cb + c) = v;
    }
    if (hbf) {
#pragma unroll
      for (int c = 0; c < CPL; c += 8) {
        u32x4 pk;
#pragma unroll
        for (int q = 0; q < 4; ++q)
          pk[q] = (unsigned int)f2bf(o[c + 2 * q]) | ((unsigned int)f2bf(o[c + 2 * q + 1]) << 16);
        *(u32x4*)(hbf + (size_t)n * DD + cb + c) = pk;
      }
    }
  }
}

extern "C" void kernel_launch(void* const* d_in, const int* in_sizes, int n_in,
                              void* d_out, int out_size, void* d_ws, size_t ws_size,
                              hipStream_t stream) {
  const float* x = (const float*)d_in[0];
  const int* ei = (const int*)d_in[1];
  const float* W1l = (const float*)d_in[2];
  const float* W1r = (const float*)d_in[3];
  const float* att1 = (const float*)d_in[4];
  const float* b1 = (const float*)d_in[5];
  const float* W2l = (const float*)d_in[6];
  const float* W2r = (const float*)d_in[7];
  const float* att2 = (const float*)d_in[8];
  const float* b2 = (const float*)d_in[9];
  const float* W3l = (const float*)d_in[10];
  const float* W3r = (const float*)d_in[11];
  const float* att3 = (const float*)d_in[12];
  const float* b3 = (const float*)d_in[13];
  float* out = (float*)d_out;

  char* p = (char*)d_ws;
  auto carve = [&](size_t bytes) {
    char* r = p;
    p += (bytes + 255) & ~(size_t)255;
    return r;
  };
  unsigned short* xl = (unsigned short*)carve((size_t)NN * 1024 * 2);
  unsigned short* xr = (unsigned short*)carve((size_t)NN * 1024 * 2);
  unsigned short* abf = (unsigned short*)carve((size_t)NN * DD * 2);
  unsigned short* wt1 = (unsigned short*)carve((size_t)2 * 1024 * DD * 2);
  unsigned short* wt2 = (unsigned short*)carve((size_t)2 * 1024 * DD * 2);
  unsigned short* wt3 = (unsigned short*)carve((size_t)2 * 512 * DD * 2);
  float* as1 = (float*)carve((size_t)8 * DD * 4);
  float* as2 = (float*)carve((size_t)8 * DD * 4);
  float* as3 = (float*)carve((size_t)4 * DD * 4);
  int* counts = (int*)carve((size_t)NN * 4);
  int* offs = (int*)carve(((size_t)NN + 1) * 4);
  int* cursor = (int*)carve((size_t)NN * 4);
  int* srcs = (int*)carve((size_t)ET * 4);
  size_t needed = (size_t)(p - (char*)d_ws);
  if (needed > ws_size) return;

  // prep (W transposes, att scales, x->bf16, counts=0) in one launch
  k_prep<<<9016, 256, 0, stream>>>(x, W1l, W1r, W2l, W2r, W3l, W3r, att1, att2, att3,
                                   wt1, wt2, wt3, as1, as2, as3, abf, counts);
  // CSR
  k_count<<<(ET + 255) / 256, 256, 0, stream>>>(ei, counts);
  k_scan<<<1, 1024, 0, stream>>>(counts, offs, cursor);
  k_fill<<<(ET + 255) / 256, 256, 0, stream>>>(ei, cursor, srcs);

  const int gx = (NN + 127) / 128;
  // layer 1
  gemm_bt<<<gx * 16, 256, 0, stream>>>(abf, wt1, xl, xr, NN, 1024, 4);
  gat_agg3<8><<<(NN + 3) / 4, 256, 0, stream>>>(xl, xr, offs, srcs, as1, b1, x, out, abf, 1);
  // layer 2
  gemm_bt<<<gx * 16, 256, 0, stream>>>(abf, wt2, xl, xr, NN, 1024, 4);
  gat_agg3<8><<<(NN + 3) / 4, 256, 0, stream>>>(xl, xr, offs, srcs, as2, b2, out, out, abf, 1);
  // layer 3
  gemm_bt<<<gx * 8, 256, 0, stream>>>(abf, wt3, xl, xr, NN, 512, 3);
  gat_agg3<4><<<(NN + 3) / 4, 256, 0, stream>>>(xl, xr, offs, srcs, as3, b3, out, out, nullptr, 0);
}